// Round 2
// baseline (9574.806 us; speedup 1.0000x reference)
//
#include <hip/hip_runtime.h>
#include <cstddef>
#include <cstdint>

// SDCN GNN: 5 × (dense GEMM + sparse A@· ) + softmax.
// Identities:
//   A@(F@W) = (A@F)@W  → layer-3 SpMM runs on the 500-wide input, not 2000-wide.
//   t4 = (0.5*relu(g3@W3)+0.5*tra3)@W4 split:
//     tra3w4:  t4  = 0.5*tra3@W4          (streaming init)
//     gemm34:  t4 += 0.5*relu(g3@W3)@W4   (register-fused epilogue)
// Dense GEMMs use a shared structure sized from measured MI355X costs:
//   - 32 rows/block (8/wave): per-wave operand reuse = 8 → B-matrix L2 traffic
//     = (#blocks × |B|), not (#waves × |B|)  [R1 was L2-bound at 40 GB]
//   - B staged in LDS [16][512] (32 KB), lane reads at 16B stride: conflict-free
//   - A read as wave-uniform global loads (scalarizable) → zero LDS cost
//   - 8 cols/lane (quads at 4*lane and 256+4*lane), pacc[8][8] in registers

constexpr int D_IN = 512;   // input width
constexpr int D1   = 500;   // enc1 width (= wide SpMM width)
constexpr int D2   = 500;   // enc2 width
constexpr int D3   = 2000;  // enc3 width
constexpr int DC   = 10;    // z / cluster width

constexpr int RS = 32;   // rows per block for stripe GEMMs (8 per wave)
constexpr int KG = 16;   // k-rows per staged group

// ---------------------------------------------------------------- CSR build
__global__ void zero_i32(int* __restrict__ p, int n) {
    int i = blockIdx.x * 256 + threadIdx.x;
    if (i < n) p[i] = 0;
}

__global__ void count_edges(const int* __restrict__ row, int E, int* __restrict__ cnt) {
    int e = blockIdx.x * 256 + threadIdx.x;
    if (e < E) atomicAdd(&cnt[row[e]], 1);
}

__global__ __launch_bounds__(1024) void scan_rowptr(const int* __restrict__ cnt, int Nr,
                                                    int* __restrict__ rp, int* __restrict__ cur) {
    __shared__ int sb[1024];
    const int t = threadIdx.x;
    int carry = 0;
    for (int base = 0; base < Nr; base += 1024) {
        int idx = base + t;
        int c = (idx < Nr) ? cnt[idx] : 0;
        sb[t] = c;
        __syncthreads();
        for (int off = 1; off < 1024; off <<= 1) {
            int add = (t >= off) ? sb[t - off] : 0;
            __syncthreads();
            sb[t] += add;
            __syncthreads();
        }
        if (idx < Nr) { int ex = carry + sb[t] - c; rp[idx] = ex; cur[idx] = ex; }
        carry += sb[1023];
        __syncthreads();
    }
    if (t == 0) rp[Nr] = carry;
}

__global__ void scatter_edges(const int* __restrict__ row, const int* __restrict__ col,
                              const float* __restrict__ val, int E,
                              int* __restrict__ cur, int* __restrict__ ci,
                              float* __restrict__ cv) {
    int e = blockIdx.x * 256 + threadIdx.x;
    if (e < E) {
        int r = row[e];
        int p = atomicAdd(&cur[r], 1);
        ci[p] = col[e];
        cv[p] = val[e];
    }
}

// ------------------------------------------------------------- stripe GEMM
// C(MxNn) = A(MxK) @ B(KxNn), Nn <= 512, Nn % 4 == 0, K % 4 == 0.
__global__ __launch_bounds__(256, 4) void gemm_stripe(const float* __restrict__ A,
                                                      const float* __restrict__ B,
                                                      float* __restrict__ C,
                                                      int M, int K, int Nn,
                                                      const float* __restrict__ zpad) {
    __shared__ float Ws[KG][512];
    const int t = threadIdx.x;
    const int lane = t & 63;
    const int wid = t >> 6;
    const int i0 = blockIdx.x * RS;
    const int rb = wid * 8;

    const float* Ar[8];
#pragma unroll
    for (int i = 0; i < 8; i++) {
        int rg = i0 + rb + i;
        rg = rg < M ? rg : M - 1;   // clamp: no OOB loads; stores guarded below
        Ar[i] = A + (size_t)rg * K;
    }

    float pacc[8][8] = {};
    const int ngroups = (K + KG - 1) / KG;

    for (int g = 0; g < ngroups; g++) {
        const int k0 = g * KG;
        const int kg = min(KG, K - k0);
        // stage B[k0..k0+kg) x [0..Nn) into Ws (zero-fill the rest)
        float4 st[8];
#pragma unroll
        for (int q = 0; q < 8; q++) {
            int e = t + 256 * q;                 // e < 2048
            int kk = e >> 7, jj4 = (e & 127) << 2;
            const float* src = (kk < kg && jj4 < Nn)
                                   ? (B + (size_t)(k0 + kk) * Nn + jj4)
                                   : zpad;
            st[q] = *reinterpret_cast<const float4*>(src);
        }
        __syncthreads();   // all waves done reading previous Ws
#pragma unroll
        for (int q = 0; q < 8; q++) {
            int e = t + 256 * q;
            int kk = e >> 7, jj4 = (e & 127) << 2;
            *reinterpret_cast<float4*>(&Ws[kk][jj4]) = st[q];
        }
        __syncthreads();   // Ws visible
        // compute
        for (int k4 = 0; k4 < kg; k4 += 4) {
            float4 ga[8];
#pragma unroll
            for (int i = 0; i < 8; i++)   // wave-uniform → scalarizable loads
                ga[i] = *reinterpret_cast<const float4*>(Ar[i] + k0 + k4);
#pragma unroll
            for (int q = 0; q < 4; q++) {
                float4 wlo = *reinterpret_cast<const float4*>(&Ws[k4 + q][4 * lane]);
                float4 whi = *reinterpret_cast<const float4*>(&Ws[k4 + q][256 + 4 * lane]);
#pragma unroll
                for (int i = 0; i < 8; i++) {
                    const float av = reinterpret_cast<const float*>(&ga[i])[q];
                    pacc[i][0] += av * wlo.x;
                    pacc[i][1] += av * wlo.y;
                    pacc[i][2] += av * wlo.z;
                    pacc[i][3] += av * wlo.w;
                    pacc[i][4] += av * whi.x;
                    pacc[i][5] += av * whi.y;
                    pacc[i][6] += av * whi.z;
                    pacc[i][7] += av * whi.w;
                }
            }
        }
    }
    // store (full quads only; Nn % 4 == 0 so quads never straddle the edge)
#pragma unroll
    for (int i = 0; i < 8; i++) {
        int row = i0 + rb + i;
        if (row >= M) break;
        if (4 * lane + 4 <= Nn) {
            float4 lo;
            lo.x = pacc[i][0]; lo.y = pacc[i][1]; lo.z = pacc[i][2]; lo.w = pacc[i][3];
            *reinterpret_cast<float4*>(C + (size_t)row * Nn + 4 * lane) = lo;
        }
        if (260 + 4 * lane <= Nn) {
            float4 hi;
            hi.x = pacc[i][4]; hi.y = pacc[i][5]; hi.z = pacc[i][6]; hi.w = pacc[i][7];
            *reinterpret_cast<float4*>(C + (size_t)row * Nn + 256 + 4 * lane) = hi;
        }
    }
}

// ---------------------------------------------------- fused gemm3+relu+gemm4
// t4[i,c] += 0.5 * sum_j relu((g3@W3)[i,j]) * W4[j,c]    (t4 pre-set by tra3w4)
// Same structure as gemm_stripe; j covered in 4 chunks of 512; per-chunk
// register epilogue: relu + W4 contraction (half-split to cap VGPR), 64-lane
// shuffle butterfly, lane-0 accumulate into t4.
__global__ __launch_bounds__(256, 4) void gemm34(const float* __restrict__ g3,
                                                 const float* __restrict__ W3,
                                                 const float* __restrict__ W4,
                                                 float* __restrict__ t4,
                                                 int M, const float* __restrict__ zpad) {
    __shared__ float Ws[KG][512];
    const int t = threadIdx.x;
    const int lane = t & 63;
    const int wid = t >> 6;
    const int i0 = blockIdx.x * RS;
    const int rb = wid * 8;

    const float* Ar[8];
#pragma unroll
    for (int i = 0; i < 8; i++) {
        int rg = i0 + rb + i;
        rg = rg < M ? rg : M - 1;
        Ar[i] = g3 + (size_t)rg * D2;
    }

    for (int j0 = 0; j0 < D3; j0 += 512) {
        float pacc[8][8] = {};
        const int ngroups = (D2 + KG - 1) / KG;   // 32 (31 full + kg=4 tail)
        for (int g = 0; g < ngroups; g++) {
            const int k0 = g * KG;
            const int kg = min(KG, D2 - k0);
            float4 st[8];
#pragma unroll
            for (int q = 0; q < 8; q++) {
                int e = t + 256 * q;
                int kk = e >> 7, jj4 = (e & 127) << 2;
                const float* src = (kk < kg && j0 + jj4 < D3)
                                       ? (W3 + (size_t)(k0 + kk) * D3 + j0 + jj4)
                                       : zpad;
                st[q] = *reinterpret_cast<const float4*>(src);
            }
            __syncthreads();
#pragma unroll
            for (int q = 0; q < 8; q++) {
                int e = t + 256 * q;
                int kk = e >> 7, jj4 = (e & 127) << 2;
                *reinterpret_cast<float4*>(&Ws[kk][jj4]) = st[q];
            }
            __syncthreads();
            for (int k4 = 0; k4 < kg; k4 += 4) {
                float4 ga[8];
#pragma unroll
                for (int i = 0; i < 8; i++)
                    ga[i] = *reinterpret_cast<const float4*>(Ar[i] + k0 + k4);
#pragma unroll
                for (int q = 0; q < 4; q++) {
                    float4 wlo = *reinterpret_cast<const float4*>(&Ws[k4 + q][4 * lane]);
                    float4 whi = *reinterpret_cast<const float4*>(&Ws[k4 + q][256 + 4 * lane]);
#pragma unroll
                    for (int i = 0; i < 8; i++) {
                        const float av = reinterpret_cast<const float*>(&ga[i])[q];
                        pacc[i][0] += av * wlo.x;
                        pacc[i][1] += av * wlo.y;
                        pacc[i][2] += av * wlo.z;
                        pacc[i][3] += av * wlo.w;
                        pacc[i][4] += av * whi.x;
                        pacc[i][5] += av * whi.y;
                        pacc[i][6] += av * whi.z;
                        pacc[i][7] += av * whi.w;
                    }
                }
            }
        }
        // per-chunk epilogue: relu + W4 contraction in registers.
        // half-split over rows to keep VGPR under 128.
#pragma unroll
        for (int h = 0; h < 2; h++) {
            float ea[4][10] = {};
#pragma unroll
            for (int s = 0; s < 2; s++) {
#pragma unroll
                for (int jj = 0; jj < 4; jj++) {
                    const int jc = j0 + s * 256 + 4 * lane + jj;
                    float w4v[10];
                    if (jc < D3) {
                        const float* w4r = W4 + (size_t)jc * DC;
#pragma unroll
                        for (int u = 0; u < 5; u++) {
                            float2 f = *reinterpret_cast<const float2*>(w4r + 2 * u);
                            w4v[2 * u] = f.x;
                            w4v[2 * u + 1] = f.y;
                        }
                    } else {
#pragma unroll
                        for (int c = 0; c < 10; c++) w4v[c] = 0.f;
                    }
#pragma unroll
                    for (int i = 0; i < 4; i++) {
                        const float p = fmaxf(pacc[h * 4 + i][s * 4 + jj], 0.f);
#pragma unroll
                        for (int c = 0; c < 10; c++) ea[i][c] += p * w4v[c];
                    }
                }
            }
            // sum over 64 lanes (each lane held a disjoint j-subset)
#pragma unroll
            for (int i = 0; i < 4; i++)
#pragma unroll
                for (int c = 0; c < 10; c++) {
                    float v = ea[i][c];
                    v += __shfl_xor(v, 1, 64);
                    v += __shfl_xor(v, 2, 64);
                    v += __shfl_xor(v, 4, 64);
                    v += __shfl_xor(v, 8, 64);
                    v += __shfl_xor(v, 16, 64);
                    v += __shfl_xor(v, 32, 64);
                    ea[i][c] = v;
                }
            if (lane == 0) {
#pragma unroll
                for (int i = 0; i < 4; i++) {
                    const int row = i0 + rb + h * 4 + i;
                    if (row < M) {
                        float* dst = t4 + (size_t)row * DC;
#pragma unroll
                        for (int c = 0; c < 10; c++) dst[c] += 0.5f * ea[i][c];
                    }
                }
            }
        }
    }
}

// t4 = 0.5 * tra3 @ W4  — streaming init (reads tra3 once, 400 MB).
constexpr int RT = 16;

__global__ __launch_bounds__(256) void tra3w4(const float* __restrict__ tra3,
                                              const float* __restrict__ W4,
                                              float* __restrict__ t4) {
    const int t = threadIdx.x;
    const int r = t >> 4, l = t & 15;
    const size_t i = (size_t)blockIdx.x * RT + r;
    const float* rowp = tra3 + i * D3;
    float a[10] = {};
    for (int m = l; m < D3 / 4; m += 16) {
        float4 v = *reinterpret_cast<const float4*>(rowp + m * 4);
        const float* w4r = W4 + m * 4 * DC;
        const float vv[4] = {v.x, v.y, v.z, v.w};
#pragma unroll
        for (int q = 0; q < 4; q++)
#pragma unroll
            for (int c = 0; c < 10; c++) a[c] += vv[q] * w4r[q * DC + c];
    }
#pragma unroll
    for (int c = 0; c < 10; c++) {
        float v = a[c];
        v += __shfl_xor(v, 1, 64);
        v += __shfl_xor(v, 2, 64);
        v += __shfl_xor(v, 4, 64);
        v += __shfl_xor(v, 8, 64);
        a[c] = v;
    }
    if (l == 0) {
        float* dst = t4 + i * DC;
#pragma unroll
        for (int c = 0; c < 10; c++) dst[c] = 0.5f * a[c];
    }
}

// ------------------------------------------------- tiny GEMM: g5 = a4 @ W5
__global__ __launch_bounds__(256) void gemm10(const float* __restrict__ a4,
                                              const float* __restrict__ W5,
                                              float* __restrict__ g5, int Nr) {
    __shared__ float w5s[DC * DC];
    const int t = threadIdx.x;
    if (t < DC * DC) w5s[t] = W5[t];
    __syncthreads();
    const int i = blockIdx.x * 256 + t;
    if (i >= Nr) return;
    const float* ar = a4 + (size_t)i * DC;
    float a[DC];
#pragma unroll
    for (int u = 0; u < 5; u++) {
        float2 f = *reinterpret_cast<const float2*>(ar + 2 * u);
        a[2 * u] = f.x;
        a[2 * u + 1] = f.y;
    }
    float o[DC] = {};
#pragma unroll
    for (int k = 0; k < DC; k++)
#pragma unroll
        for (int c = 0; c < DC; c++) o[c] += a[k] * w5s[k * DC + c];
    float* dst = g5 + (size_t)i * DC;
#pragma unroll
    for (int u = 0; u < 5; u++) {
        float2 f;
        f.x = o[2 * u];
        f.y = o[2 * u + 1];
        *reinterpret_cast<float2*>(dst + 2 * u) = f;
    }
}

// ---------------------------------------------------------------- SpMM (CSR)
__global__ __launch_bounds__(256) void spmm_w(const int* __restrict__ rp,
                                              const int* __restrict__ ci,
                                              const float* __restrict__ cv,
                                              const float* __restrict__ m,
                                              float* __restrict__ out,
                                              const float* __restrict__ mix,
                                              int relu) {
    const int i = blockIdx.x, t = threadIdx.x;
    const int c0 = t, c1 = t + 256;
    float a0 = 0.f, a1 = 0.f;
    const int pb = rp[i], pe = rp[i + 1];
    for (int p = pb; p < pe; p++) {
        const int col = ci[p];
        const float v = cv[p];
        const float* mr = m + (size_t)col * D1;
        a0 += v * mr[c0];
        if (c1 < D1) a1 += v * mr[c1];
    }
    if (relu) { a0 = fmaxf(a0, 0.f); a1 = fmaxf(a1, 0.f); }
    const size_t o = (size_t)i * D1;
    if (mix) {
        out[o + c0] = 0.5f * a0 + 0.5f * mix[o + c0];
        if (c1 < D1) out[o + c1] = 0.5f * a1 + 0.5f * mix[o + c1];
    } else {
        out[o + c0] = a0;
        if (c1 < D1) out[o + c1] = a1;
    }
}

__global__ __launch_bounds__(256) void spmm_n(const int* __restrict__ rp,
                                              const int* __restrict__ ci,
                                              const float* __restrict__ cv,
                                              const float* __restrict__ m,
                                              float* __restrict__ out,
                                              const float* __restrict__ mix,
                                              int relu, int Nr) {
    const int t = threadIdx.x;
    const int lr = t / DC, c = t - lr * DC;
    if (lr >= 25) return;
    const int i = blockIdx.x * 25 + lr;
    if (i >= Nr) return;
    float a = 0.f;
    const int pb = rp[i], pe = rp[i + 1];
    for (int p = pb; p < pe; p++) a += cv[p] * m[(size_t)ci[p] * DC + c];
    if (relu) a = fmaxf(a, 0.f);
    if (mix) a = 0.5f * a + 0.5f * mix[(size_t)i * DC + c];
    out[(size_t)i * DC + c] = a;
}

// ---------------------------------------------------------------- softmax
__global__ void softmax10(const float* __restrict__ in, float* __restrict__ out, int Nr) {
    int i = blockIdx.x * 256 + threadIdx.x;
    if (i >= Nr) return;
    const float* r = in + (size_t)i * DC;
    float v[DC], mx = r[0];
#pragma unroll
    for (int c = 0; c < DC; c++) { v[c] = r[c]; mx = fmaxf(mx, v[c]); }
    float s = 0.f;
#pragma unroll
    for (int c = 0; c < DC; c++) { v[c] = __expf(v[c] - mx); s += v[c]; }
    float inv = 1.0f / s;
    float* o = out + (size_t)i * DC;
#pragma unroll
    for (int c = 0; c < DC; c++) o[c] = v[c] * inv;
}

// ---------------------------------------------------------------- launcher
extern "C" void kernel_launch(void* const* d_in, const int* in_sizes, int n_in,
                              void* d_out, int out_size, void* d_ws, size_t ws_size,
                              hipStream_t stream) {
    const float* x    = (const float*)d_in[0];
    const float* tra1 = (const float*)d_in[1];
    const float* tra2 = (const float*)d_in[2];
    const float* tra3 = (const float*)d_in[3];
    const float* z    = (const float*)d_in[4];
    const float* ev   = (const float*)d_in[5];
    const int*   erow = (const int*)d_in[6];
    const int*   ecol = (const int*)d_in[7];
    const float* W1   = (const float*)d_in[8];
    const float* W2   = (const float*)d_in[9];
    const float* W3   = (const float*)d_in[10];
    const float* W4   = (const float*)d_in[11];
    const float* W5   = (const float*)d_in[12];

    const int Nr = in_sizes[4] / DC;  // 50000
    const int E  = in_sizes[5];       // 1600000

    char* ws = (char*)d_ws;
    size_t off = 0;
    auto alloc = [&](size_t bytes) -> char* {
        char* p = ws + off;
        off = (off + bytes + 255) & ~(size_t)255;
        return p;
    };
    float* B0   = (float*)alloc((size_t)Nr * D1 * 4);
    float* B1   = (float*)alloc((size_t)Nr * D1 * 4);
    float* t4   = (float*)alloc((size_t)Nr * DC * 4);
    float* a4   = (float*)alloc((size_t)Nr * DC * 4);
    float* g5   = (float*)alloc((size_t)Nr * DC * 4);
    float* pre  = (float*)alloc((size_t)Nr * DC * 4);
    int*   rp   = (int*)alloc((size_t)(Nr + 1) * 4);
    int*   cur  = (int*)alloc((size_t)Nr * 4);
    int*   cnt  = (int*)alloc((size_t)Nr * 4);
    int*   ci   = (int*)alloc((size_t)E * 4);
    float* cv   = (float*)alloc((size_t)E * 4);
    float* zpad = (float*)alloc(256);

    const int eb = (E + 255) / 256;
    const int nb = (Nr + 255) / 256;
    const int gsb = (Nr + RS - 1) / RS;   // stripe-GEMM grid (1563)

    // CSR build + zero pad
    zero_i32<<<nb, 256, 0, stream>>>(cnt, Nr);
    zero_i32<<<1, 256, 0, stream>>>((int*)zpad, 64);
    count_edges<<<eb, 256, 0, stream>>>(erow, E, cnt);
    scan_rowptr<<<1, 1024, 0, stream>>>(cnt, Nr, rp, cur);
    scatter_edges<<<eb, 256, 0, stream>>>(erow, ecol, ev, E, cur, ci, cv);

    // t4 init (independent of the SpMM chain; must precede gemm34)
    tra3w4<<<Nr / RT, 256, 0, stream>>>(tra3, W4, t4);

    // L1: h1' = 0.5*relu(A@(x@W1)) + 0.5*tra1
    gemm_stripe<<<gsb, 256, 0, stream>>>(x, W1, B0, Nr, D_IN, D1, zpad);
    spmm_w<<<Nr, 256, 0, stream>>>(rp, ci, cv, B0, B1, tra1, 1);
    // L2: h2' = 0.5*relu(A@(h1'@W2)) + 0.5*tra2
    gemm_stripe<<<gsb, 256, 0, stream>>>(B1, W2, B0, Nr, D1, D2, zpad);
    spmm_w<<<Nr, 256, 0, stream>>>(rp, ci, cv, B0, B1, tra2, 1);
    // L3 (SpMM first): g3 = A@h2'
    spmm_w<<<Nr, 256, 0, stream>>>(rp, ci, cv, B1, B0, nullptr, 0);
    // L3 GEMM + relu + L4 GEMM, register-fused: t4 += 0.5*relu(g3@W3)@W4
    gemm34<<<gsb, 256, 0, stream>>>(B0, W3, W4, t4, Nr, zpad);
    // L4 SpMM: a4 = 0.5*relu(A@t4) + 0.5*z
    spmm_n<<<(Nr + 24) / 25, 256, 0, stream>>>(rp, ci, cv, t4, a4, z, 1, Nr);
    // L5: pre = A@(a4@W5)
    gemm10<<<nb, 256, 0, stream>>>(a4, W5, g5, Nr);
    spmm_n<<<(Nr + 24) / 25, 256, 0, stream>>>(rp, ci, cv, g5, pre, nullptr, 0, Nr);
    // softmax
    softmax10<<<nb, 256, 0, stream>>>(pre, (float*)d_out, Nr);
}

// Round 3
// 5321.841 us; speedup vs baseline: 1.7992x; 1.7992x over previous
//
#include <hip/hip_runtime.h>
#include <cstddef>
#include <cstdint>

// SDCN GNN: 5 × (dense GEMM + sparse A@· ) + softmax.
// Identities:
//   A@(F@W) = (A@F)@W  → layer-3 SpMM runs on the 500-wide input, not 2000-wide.
//   t4 = (0.5*relu(g3@W3)+0.5*tra3)@W4 split:
//     tra3w4:  t4  = 0.5*tra3@W4          (streaming init)
//     gemm34:  t4 += 0.5*relu(g3@W3)@W4   (register-fused epilogue)
// gemm34 v5 design (from R1/R2 post-mortems):
//   - R1 (per-wave rows): each wave read all 4MB of W3 → 40 GB L2 → L2-BW-bound.
//   - R2 (LDS-staged W3): 145+ live VGPRs vs 128 cap → spilled (14 GB scratch).
//   - v5: rows are BLOCK-uniform (20/block); waves split j. W3 L2 = 10 GB.
//     g3 addresses depend only on blockIdx/k → scalar s_load (A in SGPRs):
//     no LDS tile, no staging barrier, no ga VGPRs. Main-loop live ≈ 105 VGPR.

constexpr int D_IN = 512;   // input width
constexpr int D1   = 500;   // enc1 width (= wide SpMM width)
constexpr int D2   = 500;   // enc2 width
constexpr int D3   = 2000;  // enc3 width
constexpr int DC   = 10;    // z / cluster width

// ---------------------------------------------------------------- CSR build
__global__ void zero_i32(int* __restrict__ p, int n) {
    int i = blockIdx.x * 256 + threadIdx.x;
    if (i < n) p[i] = 0;
}

__global__ void count_edges(const int* __restrict__ row, int E, int* __restrict__ cnt) {
    int e = blockIdx.x * 256 + threadIdx.x;
    if (e < E) atomicAdd(&cnt[row[e]], 1);
}

__global__ __launch_bounds__(1024) void scan_rowptr(const int* __restrict__ cnt, int Nr,
                                                    int* __restrict__ rp, int* __restrict__ cur) {
    __shared__ int sb[1024];
    const int t = threadIdx.x;
    int carry = 0;
    for (int base = 0; base < Nr; base += 1024) {
        int idx = base + t;
        int c = (idx < Nr) ? cnt[idx] : 0;
        sb[t] = c;
        __syncthreads();
        for (int off = 1; off < 1024; off <<= 1) {
            int add = (t >= off) ? sb[t - off] : 0;
            __syncthreads();
            sb[t] += add;
            __syncthreads();
        }
        if (idx < Nr) { int ex = carry + sb[t] - c; rp[idx] = ex; cur[idx] = ex; }
        carry += sb[1023];
        __syncthreads();
    }
    if (t == 0) rp[Nr] = carry;
}

__global__ void scatter_edges(const int* __restrict__ row, const int* __restrict__ col,
                              const float* __restrict__ val, int E,
                              int* __restrict__ cur, int* __restrict__ ci,
                              float* __restrict__ cv) {
    int e = blockIdx.x * 256 + threadIdx.x;
    if (e < E) {
        int r = row[e];
        int p = atomicAdd(&cur[r], 1);
        ci[p] = col[e];
        cv[p] = val[e];
    }
}

// ---------------------------------------------------------------- dense GEMM
// C(MxN) = A(MxK) @ B(KxN), fp32 row-major, 64x64 tile, 4x4 per thread.
// (proven in R0/R1 — used for L1 and L2)
constexpr int BM = 64, BN = 64, BK = 16;

__global__ __launch_bounds__(256) void gemm_tiled(const float* __restrict__ A,
                                                  const float* __restrict__ B,
                                                  float* __restrict__ C,
                                                  int M, int K, int Nn) {
    __shared__ float As[BM][BK + 1];
    __shared__ float Bs[BK][BN];
    const int tid = threadIdx.x;
    const int tx = tid & 15, ty = tid >> 4;
    const int rowBase = blockIdx.y * BM, colBase = blockIdx.x * BN;
    float acc[4][4] = {};
    for (int k0 = 0; k0 < K; k0 += BK) {
        for (int e = tid; e < BM * BK; e += 256) {
            int m = e >> 4, k = e & 15;
            int gr = rowBase + m, gk = k0 + k;
            As[m][k] = (gr < M && gk < K) ? A[(size_t)gr * K + gk] : 0.f;
        }
        for (int e = tid; e < BK * BN; e += 256) {
            int k = e >> 6, n = e & 63;
            int gk = k0 + k, gc = colBase + n;
            Bs[k][n] = (gk < K && gc < Nn) ? B[(size_t)gk * Nn + gc] : 0.f;
        }
        __syncthreads();
        for (int k = 0; k < BK; k++) {
            float a[4], b[4];
#pragma unroll
            for (int i = 0; i < 4; i++) a[i] = As[ty * 4 + i][k];
#pragma unroll
            for (int j = 0; j < 4; j++) b[j] = Bs[k][tx * 4 + j];
#pragma unroll
            for (int i = 0; i < 4; i++)
#pragma unroll
                for (int j = 0; j < 4; j++) acc[i][j] += a[i] * b[j];
        }
        __syncthreads();
    }
#pragma unroll
    for (int i = 0; i < 4; i++) {
        int gr = rowBase + ty * 4 + i;
        if (gr >= M) continue;
#pragma unroll
        for (int j = 0; j < 4; j++) {
            int gc = colBase + tx * 4 + j;
            if (gc < Nn) C[(size_t)gr * Nn + gc] = acc[i][j];
        }
    }
}

// ---------------------------------------------------- fused gemm3+relu+gemm4
// t4[i,c] += 0.5 * sum_j relu((g3@W3)[i,j]) * W4[j,c]    (t4 pre-set by tra3w4)
// Block = 256 thr (4 waves) owns RB=20 rows (blockIdx-uniform).
// Wave w covers j-chunks {w, w+4} of 8 (256 cols each, 4 cols/lane).
// g3 loads are uniform (blockIdx + loop k only) → scalar loads, A in SGPRs.
// W3: per-lane float4 stream, ping-pong prefetched (2 k-rows per group).
// Per-chunk epilogue: relu + W4 in registers → 64-lane butterfly → per-wave
// LDS partials (3.2 KB) → one barrier → deterministic t4 +=.
constexpr int RB = 20;   // rows per block (50000 % 20 == 0)

__global__ __launch_bounds__(256) void gemm34(const float* __restrict__ g3,
                                              const float* __restrict__ W3,
                                              const float* __restrict__ W4,
                                              float* __restrict__ t4) {
    __shared__ float part[4][RB][DC];   // 3200 B
    const int t = threadIdx.x;
    const int lane = t & 63;
    const int wid = t >> 6;
    const int i0 = blockIdx.x * RB;                 // uniform rows
    const float* rowbase = g3 + (size_t)i0 * D2;    // uniform base

    // zero this wave's partial slab (same-wave ordering, no barrier needed)
    for (int e = lane; e < RB * DC; e += 64) part[wid][e / DC][e % DC] = 0.f;

    for (int cc = 0; cc < 2; cc++) {
        const int chunk = wid + 4 * cc;             // 0..7
        const int j4 = chunk * 256 + 4 * lane;      // this lane's 4 cols
        const float* w3p = W3 + j4;
        float pacc[RB][4] = {};

        float4 wa0, wa1, wb0, wb1;
        auto load_a = [&](float4& d0, float4& d1, int k) {
            d0 = *reinterpret_cast<const float4*>(w3p + (size_t)k * D3);
            d1 = *reinterpret_cast<const float4*>(w3p + (size_t)(k + 1) * D3);
        };
        auto fma_grp = [&](const float4& w0, const float4& w1, int k) {
#pragma unroll
            for (int i = 0; i < RB; i++) {
                const float* ar = rowbase + (size_t)i * D2 + k;   // uniform → s_load
                const float a0 = ar[0], a1 = ar[1];
                pacc[i][0] += a0 * w0.x; pacc[i][1] += a0 * w0.y;
                pacc[i][2] += a0 * w0.z; pacc[i][3] += a0 * w0.w;
                pacc[i][0] += a1 * w1.x; pacc[i][1] += a1 * w1.y;
                pacc[i][2] += a1 * w1.z; pacc[i][3] += a1 * w1.w;
            }
        };

        // 250 k-groups of 2: ping-pong prefetch, 124 double-iterations + tail
        load_a(wa0, wa1, 0);
        for (int k = 0; k < D2 - 4; k += 4) {
            load_a(wb0, wb1, k + 2);
            fma_grp(wa0, wa1, k);
            load_a(wa0, wa1, k + 4);
            fma_grp(wb0, wb1, k + 2);
        }
        load_a(wb0, wb1, D2 - 2);
        fma_grp(wa0, wa1, D2 - 4);
        fma_grp(wb0, wb1, D2 - 2);

        // epilogue: relu + W4 contraction, rows in quarters of 4
#pragma unroll
        for (int qr = 0; qr < RB / 4; qr++) {
            float ea[4][DC] = {};
#pragma unroll
            for (int jj = 0; jj < 4; jj++) {
                const float* w4r = W4 + (size_t)(j4 + jj) * DC;
                float w4v[DC];
#pragma unroll
                for (int u = 0; u < 5; u++) {
                    float2 f = *reinterpret_cast<const float2*>(w4r + 2 * u);
                    w4v[2 * u] = f.x;
                    w4v[2 * u + 1] = f.y;
                }
#pragma unroll
                for (int i = 0; i < 4; i++) {
                    const float p = fmaxf(pacc[qr * 4 + i][jj], 0.f);
#pragma unroll
                    for (int c = 0; c < DC; c++) ea[i][c] += p * w4v[c];
                }
            }
#pragma unroll
            for (int i = 0; i < 4; i++)
#pragma unroll
                for (int c = 0; c < DC; c++) {
                    float v = ea[i][c];
                    v += __shfl_xor(v, 1, 64);
                    v += __shfl_xor(v, 2, 64);
                    v += __shfl_xor(v, 4, 64);
                    v += __shfl_xor(v, 8, 64);
                    v += __shfl_xor(v, 16, 64);
                    v += __shfl_xor(v, 32, 64);
                    if (lane == c) part[wid][qr * 4 + i][c] += v;
                }
        }
    }

    __syncthreads();
    // deterministic reduce of the 4 wave-partials, accumulate into t4
    for (int e = t; e < RB * DC; e += 256) {
        const int r = e / DC, c = e - r * DC;
        float s = part[0][r][c] + part[1][r][c] + part[2][r][c] + part[3][r][c];
        t4[(size_t)(i0 + r) * DC + c] += 0.5f * s;
    }
}

// t4 = 0.5 * tra3 @ W4  — streaming init (reads tra3 once, 400 MB).
constexpr int RT = 16;

__global__ __launch_bounds__(256) void tra3w4(const float* __restrict__ tra3,
                                              const float* __restrict__ W4,
                                              float* __restrict__ t4) {
    const int t = threadIdx.x;
    const int r = t >> 4, l = t & 15;
    const size_t i = (size_t)blockIdx.x * RT + r;
    const float* rowp = tra3 + i * D3;
    float a[10] = {};
    for (int m = l; m < D3 / 4; m += 16) {
        float4 v = *reinterpret_cast<const float4*>(rowp + m * 4);
        const float* w4r = W4 + m * 4 * DC;
        const float vv[4] = {v.x, v.y, v.z, v.w};
#pragma unroll
        for (int q = 0; q < 4; q++)
#pragma unroll
            for (int c = 0; c < 10; c++) a[c] += vv[q] * w4r[q * DC + c];
    }
#pragma unroll
    for (int c = 0; c < 10; c++) {
        float v = a[c];
        v += __shfl_xor(v, 1, 64);
        v += __shfl_xor(v, 2, 64);
        v += __shfl_xor(v, 4, 64);
        v += __shfl_xor(v, 8, 64);
        a[c] = v;
    }
    if (l == 0) {
        float* dst = t4 + i * DC;
#pragma unroll
        for (int c = 0; c < 10; c++) dst[c] = 0.5f * a[c];
    }
}

// ------------------------------------------------- tiny GEMM: g5 = a4 @ W5
__global__ __launch_bounds__(256) void gemm10(const float* __restrict__ a4,
                                              const float* __restrict__ W5,
                                              float* __restrict__ g5, int Nr) {
    __shared__ float w5s[DC * DC];
    const int t = threadIdx.x;
    if (t < DC * DC) w5s[t] = W5[t];
    __syncthreads();
    const int i = blockIdx.x * 256 + t;
    if (i >= Nr) return;
    const float* ar = a4 + (size_t)i * DC;
    float a[DC];
#pragma unroll
    for (int u = 0; u < 5; u++) {
        float2 f = *reinterpret_cast<const float2*>(ar + 2 * u);
        a[2 * u] = f.x;
        a[2 * u + 1] = f.y;
    }
    float o[DC] = {};
#pragma unroll
    for (int k = 0; k < DC; k++)
#pragma unroll
        for (int c = 0; c < DC; c++) o[c] += a[k] * w5s[k * DC + c];
    float* dst = g5 + (size_t)i * DC;
#pragma unroll
    for (int u = 0; u < 5; u++) {
        float2 f;
        f.x = o[2 * u];
        f.y = o[2 * u + 1];
        *reinterpret_cast<float2*>(dst + 2 * u) = f;
    }
}

// ---------------------------------------------------------------- SpMM (CSR)
__global__ __launch_bounds__(256) void spmm_w(const int* __restrict__ rp,
                                              const int* __restrict__ ci,
                                              const float* __restrict__ cv,
                                              const float* __restrict__ m,
                                              float* __restrict__ out,
                                              const float* __restrict__ mix,
                                              int relu) {
    const int i = blockIdx.x, t = threadIdx.x;
    const int c0 = t, c1 = t + 256;
    float a0 = 0.f, a1 = 0.f;
    const int pb = rp[i], pe = rp[i + 1];
    for (int p = pb; p < pe; p++) {
        const int col = ci[p];
        const float v = cv[p];
        const float* mr = m + (size_t)col * D1;
        a0 += v * mr[c0];
        if (c1 < D1) a1 += v * mr[c1];
    }
    if (relu) { a0 = fmaxf(a0, 0.f); a1 = fmaxf(a1, 0.f); }
    const size_t o = (size_t)i * D1;
    if (mix) {
        out[o + c0] = 0.5f * a0 + 0.5f * mix[o + c0];
        if (c1 < D1) out[o + c1] = 0.5f * a1 + 0.5f * mix[o + c1];
    } else {
        out[o + c0] = a0;
        if (c1 < D1) out[o + c1] = a1;
    }
}

__global__ __launch_bounds__(256) void spmm_n(const int* __restrict__ rp,
                                              const int* __restrict__ ci,
                                              const float* __restrict__ cv,
                                              const float* __restrict__ m,
                                              float* __restrict__ out,
                                              const float* __restrict__ mix,
                                              int relu, int Nr) {
    const int t = threadIdx.x;
    const int lr = t / DC, c = t - lr * DC;
    if (lr >= 25) return;
    const int i = blockIdx.x * 25 + lr;
    if (i >= Nr) return;
    float a = 0.f;
    const int pb = rp[i], pe = rp[i + 1];
    for (int p = pb; p < pe; p++) a += cv[p] * m[(size_t)ci[p] * DC + c];
    if (relu) a = fmaxf(a, 0.f);
    if (mix) a = 0.5f * a + 0.5f * mix[(size_t)i * DC + c];
    out[(size_t)i * DC + c] = a;
}

// ---------------------------------------------------------------- softmax
__global__ void softmax10(const float* __restrict__ in, float* __restrict__ out, int Nr) {
    int i = blockIdx.x * 256 + threadIdx.x;
    if (i >= Nr) return;
    const float* r = in + (size_t)i * DC;
    float v[DC], mx = r[0];
#pragma unroll
    for (int c = 0; c < DC; c++) { v[c] = r[c]; mx = fmaxf(mx, v[c]); }
    float s = 0.f;
#pragma unroll
    for (int c = 0; c < DC; c++) { v[c] = __expf(v[c] - mx); s += v[c]; }
    float inv = 1.0f / s;
    float* o = out + (size_t)i * DC;
#pragma unroll
    for (int c = 0; c < DC; c++) o[c] = v[c] * inv;
}

// ---------------------------------------------------------------- launcher
extern "C" void kernel_launch(void* const* d_in, const int* in_sizes, int n_in,
                              void* d_out, int out_size, void* d_ws, size_t ws_size,
                              hipStream_t stream) {
    const float* x    = (const float*)d_in[0];
    const float* tra1 = (const float*)d_in[1];
    const float* tra2 = (const float*)d_in[2];
    const float* tra3 = (const float*)d_in[3];
    const float* z    = (const float*)d_in[4];
    const float* ev   = (const float*)d_in[5];
    const int*   erow = (const int*)d_in[6];
    const int*   ecol = (const int*)d_in[7];
    const float* W1   = (const float*)d_in[8];
    const float* W2   = (const float*)d_in[9];
    const float* W3   = (const float*)d_in[10];
    const float* W4   = (const float*)d_in[11];
    const float* W5   = (const float*)d_in[12];

    const int Nr = in_sizes[4] / DC;  // 50000
    const int E  = in_sizes[5];       // 1600000

    char* ws = (char*)d_ws;
    size_t off = 0;
    auto alloc = [&](size_t bytes) -> char* {
        char* p = ws + off;
        off = (off + bytes + 255) & ~(size_t)255;
        return p;
    };
    float* B0  = (float*)alloc((size_t)Nr * D1 * 4);
    float* B1  = (float*)alloc((size_t)Nr * D1 * 4);
    float* t4  = (float*)alloc((size_t)Nr * DC * 4);
    float* a4  = (float*)alloc((size_t)Nr * DC * 4);
    float* g5  = (float*)alloc((size_t)Nr * DC * 4);
    float* pre = (float*)alloc((size_t)Nr * DC * 4);
    int*   rp  = (int*)alloc((size_t)(Nr + 1) * 4);
    int*   cur = (int*)alloc((size_t)Nr * 4);
    int*   cnt = (int*)alloc((size_t)Nr * 4);
    int*   ci  = (int*)alloc((size_t)E * 4);
    float* cv  = (float*)alloc((size_t)E * 4);

    const int eb = (E + 255) / 256;
    const int nb = (Nr + 255) / 256;

    // CSR build
    zero_i32<<<nb, 256, 0, stream>>>(cnt, Nr);
    count_edges<<<eb, 256, 0, stream>>>(erow, E, cnt);
    scan_rowptr<<<1, 1024, 0, stream>>>(cnt, Nr, rp, cur);
    scatter_edges<<<eb, 256, 0, stream>>>(erow, ecol, ev, E, cur, ci, cv);

    // t4 init (independent of the SpMM chain; must precede gemm34)
    tra3w4<<<Nr / RT, 256, 0, stream>>>(tra3, W4, t4);

    auto gg = [&](int M, int Nn) { return dim3((Nn + BN - 1) / BN, (M + BM - 1) / BM); };

    // L1: h1' = 0.5*relu(A@(x@W1)) + 0.5*tra1
    gemm_tiled<<<gg(Nr, D1), 256, 0, stream>>>(x, W1, B0, Nr, D_IN, D1);
    spmm_w<<<Nr, 256, 0, stream>>>(rp, ci, cv, B0, B1, tra1, 1);
    // L2: h2' = 0.5*relu(A@(h1'@W2)) + 0.5*tra2
    gemm_tiled<<<gg(Nr, D2), 256, 0, stream>>>(B1, W2, B0, Nr, D1, D2);
    spmm_w<<<Nr, 256, 0, stream>>>(rp, ci, cv, B0, B1, tra2, 1);
    // L3 (SpMM first): g3 = A@h2'
    spmm_w<<<Nr, 256, 0, stream>>>(rp, ci, cv, B1, B0, nullptr, 0);
    // L3 GEMM + relu + L4 GEMM, register-fused: t4 += 0.5*relu(g3@W3)@W4
    gemm34<<<Nr / RB, 256, 0, stream>>>(B0, W3, W4, t4);
    // L4 SpMM: a4 = 0.5*relu(A@t4) + 0.5*z
    spmm_n<<<(Nr + 24) / 25, 256, 0, stream>>>(rp, ci, cv, t4, a4, z, 1, Nr);
    // L5: pre = A@(a4@W5)
    gemm10<<<nb, 256, 0, stream>>>(a4, W5, g5, Nr);
    spmm_n<<<(Nr + 24) / 25, 256, 0, stream>>>(rp, ci, cv, g5, pre, nullptr, 0, Nr);
    // softmax
    softmax10<<<nb, 256, 0, stream>>>(pre, (float*)d_out, Nr);
}